// Round 1
// 345.326 us; speedup vs baseline: 1.0092x; 1.0092x over previous
//
#include <hip/hip_runtime.h>

#define N_NODES 50000
#define E_EDGES 800000
#define D 256
#define L 128
#define CAP 64   // max in-degree bucket capacity; Poisson(16) tail => P(overflow) ~ 1e-19

typedef __attribute__((ext_vector_type(8))) short bf16x8;
typedef __attribute__((ext_vector_type(4))) float f32x4;

__device__ __forceinline__ float bf2f(unsigned short u) {
    union { unsigned int i; float f; } v; v.i = ((unsigned int)u) << 16; return v.f;
}
__device__ __forceinline__ unsigned short f2bf(float f) {  // round-to-nearest-even
    union { float f; unsigned int i; } v; v.f = f;
    unsigned int r = v.i + 0x7fffu + ((v.i >> 16) & 1u);
    return (unsigned short)(r >> 16);
}

__global__ __launch_bounds__(256) void zero_i(int* __restrict__ p, int n) {
    int i = blockIdx.x * 256 + threadIdx.x;
    if (i < n) p[i] = 0;
}

// Single-pass bucket build: cursor ends up = in-degree.
__global__ __launch_bounds__(256) void fill_fixed(const int* __restrict__ src,
                                                  const int* __restrict__ dst,
                                                  int* __restrict__ cursor,
                                                  int* __restrict__ bucket) {
    int e = blockIdx.x * 256 + threadIdx.x;
    if (e >= E_EDGES) return;
    int d = dst[e];
    int pos = atomicAdd(&cursor[d], 1);
    if (pos < CAP) bucket[d * CAP + pos] = src[e];
}

__global__ __launch_bounds__(256) void dinv_fin(const int* __restrict__ cursor,
                                                float* __restrict__ dinv) {
    int i = blockIdx.x * 256 + threadIdx.x;
    if (i < N_NODES) dinv[i] = rsqrtf((float)cursor[i] + 1.0f);
}

// Transpose + split weights into [n][k] bf16 hi/lo. Blocks 0..255: W1 (n=b, k=t).
// Blocks 256..511: Wcat = [Wmu | Wlv] (n=b-256, k=t). Block 256 also fills bcat.
__global__ __launch_bounds__(256) void prep_w(
    const float* __restrict__ W1, const float* __restrict__ Wmu,
    const float* __restrict__ Wlv, const float* __restrict__ bmu,
    const float* __restrict__ blv,
    unsigned short* __restrict__ W1h, unsigned short* __restrict__ W1l,
    unsigned short* __restrict__ Wch, unsigned short* __restrict__ Wcl,
    float* __restrict__ bcat) {
    int b = blockIdx.x, t = threadIdx.x;
    if (b < 256) {
        int n = b, k = t;
        float w = W1[k * 256 + n];
        unsigned short h = f2bf(w);
        W1h[n * 256 + k] = h;
        W1l[n * 256 + k] = f2bf(w - bf2f(h));
    } else {
        int n = b - 256, k = t;
        float w = (n < 128) ? Wmu[k * 128 + n] : Wlv[k * 128 + (n - 128)];
        unsigned short h = f2bf(w);
        Wch[n * 256 + k] = h;
        Wcl[n * 256 + k] = f2bf(w - bf2f(h));
        if (b == 256) bcat[t] = (t < 128) ? bmu[t] : blv[t - 128];
    }
}

// MFMA GEMM: C[M,256] = A_f32[M,256] @ (Bh+Bl)[256,256], fp32-split 3-term.
// A fp32 row-major, split to bf16 hi/lo in-register. Bt* transposed [n][k] bf16.
// Block = 64 rows x 256 cols, 4 waves x 16 rows -> grid 782 (3 blocks/CU).
__global__ __launch_bounds__(256, 3) void gemm_mfma(
    const float* __restrict__ A,
    const unsigned short* __restrict__ Bth, const unsigned short* __restrict__ Btl,
    unsigned short* __restrict__ Hout,
    float* __restrict__ mu, float* __restrict__ lv,
    const float* __restrict__ bias, int M, int mode)
{
    __shared__ unsigned short Bsh[256 * 32];
    __shared__ unsigned short Bsl[256 * 32];
    const int t = threadIdx.x;
    const int lane = t & 63, wave = t >> 6;
    const int row0 = blockIdx.x * 64 + wave * 16;
    const int m_ = lane & 15, q = lane >> 4;
    int rA = row0 + m_; if (rA >= M) rA = M - 1;
    const float* Ap = A + (size_t)rA * 256;
    const int bn = t >> 2;   // B staging: base row 0..63
    const int bc = t & 3;    // chunk 0..3

    f32x4 acc[16];
    const f32x4 zf = {0.f, 0.f, 0.f, 0.f};
#pragma unroll
    for (int nt = 0; nt < 16; ++nt) acc[nt] = zf;

    for (int ks = 0; ks < 8; ++ks) {
        const int k0 = ks * 32;
        bf16x8 gbh[4], gbl[4];
#pragma unroll
        for (int i = 0; i < 4; ++i) {
            int n = bn + i * 64;
            gbh[i] = *(const bf16x8*)(Bth + n * 256 + k0 + bc * 8);
            gbl[i] = *(const bf16x8*)(Btl + n * 256 + k0 + bc * 8);
        }
        float4 av0 = *(const float4*)(Ap + k0 + q * 8);
        float4 av1 = *(const float4*)(Ap + k0 + q * 8 + 4);
        __syncthreads();
#pragma unroll
        for (int i = 0; i < 4; ++i) {
            int n = bn + i * 64;
            int cc = (bc ^ ((n >> 1) & 3)) * 8;
            *(bf16x8*)&Bsh[n * 32 + cc] = gbh[i];
            *(bf16x8*)&Bsl[n * 32 + cc] = gbl[i];
        }
        float af[8] = {av0.x, av0.y, av0.z, av0.w, av1.x, av1.y, av1.z, av1.w};
        bf16x8 ah, al;
#pragma unroll
        for (int j = 0; j < 8; ++j) {
            unsigned short h = f2bf(af[j]);
            ah[j] = (short)h;
            al[j] = (short)f2bf(af[j] - bf2f(h));
        }
        __syncthreads();
#pragma unroll
        for (int nt = 0; nt < 16; ++nt) {
            int n = nt * 16 + m_;
            int cr = (q ^ ((n >> 1) & 3)) * 8;
            bf16x8 bh = *(const bf16x8*)&Bsh[n * 32 + cr];
            bf16x8 bl = *(const bf16x8*)&Bsl[n * 32 + cr];
            acc[nt] = __builtin_amdgcn_mfma_f32_16x16x32_bf16(ah, bh, acc[nt], 0, 0, 0);
            acc[nt] = __builtin_amdgcn_mfma_f32_16x16x32_bf16(ah, bl, acc[nt], 0, 0, 0);
            acc[nt] = __builtin_amdgcn_mfma_f32_16x16x32_bf16(al, bh, acc[nt], 0, 0, 0);
        }
    }
    // epilogue: C/D layout col=lane&15, row=(lane>>4)*4+reg  [m89/m91 verified]
    int rbase = row0 + q * 4;
#pragma unroll
    for (int r = 0; r < 4; ++r) {
        int grow = rbase + r;
        if (grow >= M) continue;
#pragma unroll
        for (int nt = 0; nt < 16; ++nt) {
            int gcol = nt * 16 + m_;
            float v = acc[nt][r];
            if (mode == 0) {
                Hout[(size_t)grow * 256 + gcol] = f2bf(v);
            } else {
                v += bias[gcol];
                if (gcol < 128) mu[(size_t)grow * 128 + gcol] = v;
                else            lv[(size_t)grow * 128 + (gcol - 128)] = v;
            }
        }
    }
}

// Two dst nodes per wave: each 32-lane half owns one node, 8 bf16 cols/lane
// (16 B loads; one full 512 B row per half-wave memory op, 2 rows per wave op).
// Edge metadata (src, w) preloaded into lane registers (lane j of each half
// holds edge j; second reg covers edges 32..63), broadcast per-edge via __shfl
// with the half-select bit (lane&32). 4-deep unroll -> 8 rows in flight/wave.
// mode 0: Z = relu(agg + bias) -> bf16. mode 1: Y -> fp32.
__global__ __launch_bounds__(256) void gather_pre(
    const unsigned short* __restrict__ Hs,
    const int* __restrict__ bucket, const int* __restrict__ cnt_,
    const float* __restrict__ dinv, const float* __restrict__ bias,
    unsigned short* __restrict__ OutZ, float* __restrict__ OutY, int mode)
{
    const int lane = threadIdx.x & 63;
    const int hl = lane & 31;                 // lane within half-wave
    const int bb = lane & 32;                 // half-select for shfl index
    const int node = blockIdx.x * 8 + (threadIdx.x >> 5);   // 8 nodes/block
    const int col = hl * 8;                   // 8 bf16 columns per lane
    int cnt = cnt_[node]; if (cnt > CAP) cnt = CAP;
    float dn = dinv[node];

    // preload: half-lane j owns edge j (reg0) and edge j+32 (reg1)
    int   s0r = 0, s1r = 0;
    float w0r = 0.f, w1r = 0.f;
    if (hl < cnt)      { s0r = bucket[node * CAP + hl];      w0r = dinv[s0r] * dn; }
    if (hl + 32 < cnt) { s1r = bucket[node * CAP + 32 + hl]; w1r = dinv[s1r] * dn; }

    // start accumulator with the self-loop term (norm_ii = 1/deg = dn*dn)
    float sl = dn * dn;
    bf16x8 hv = *(const bf16x8*)(Hs + (size_t)node * D + col);
    float a[8];
#pragma unroll
    for (int p = 0; p < 8; ++p) a[p] = bf2f((unsigned short)hv[p]) * sl;

    const int cnt0 = cnt < 32 ? cnt : 32;
    int j = 0;
    for (; j + 3 < cnt0; j += 4) {
        int t0 = __shfl(s0r, bb + j,     64), t1 = __shfl(s0r, bb + j + 1, 64);
        int t2 = __shfl(s0r, bb + j + 2, 64), t3 = __shfl(s0r, bb + j + 3, 64);
        float w0 = __shfl(w0r, bb + j,     64), w1 = __shfl(w0r, bb + j + 1, 64);
        float w2 = __shfl(w0r, bb + j + 2, 64), w3 = __shfl(w0r, bb + j + 3, 64);
        bf16x8 u0 = *(const bf16x8*)(Hs + (size_t)t0 * D + col);
        bf16x8 u1 = *(const bf16x8*)(Hs + (size_t)t1 * D + col);
        bf16x8 u2 = *(const bf16x8*)(Hs + (size_t)t2 * D + col);
        bf16x8 u3 = *(const bf16x8*)(Hs + (size_t)t3 * D + col);
#pragma unroll
        for (int p = 0; p < 8; ++p) a[p] = fmaf(bf2f((unsigned short)u0[p]), w0, a[p]);
#pragma unroll
        for (int p = 0; p < 8; ++p) a[p] = fmaf(bf2f((unsigned short)u1[p]), w1, a[p]);
#pragma unroll
        for (int p = 0; p < 8; ++p) a[p] = fmaf(bf2f((unsigned short)u2[p]), w2, a[p]);
#pragma unroll
        for (int p = 0; p < 8; ++p) a[p] = fmaf(bf2f((unsigned short)u3[p]), w3, a[p]);
    }
    for (; j < cnt0; ++j) {
        int   t0 = __shfl(s0r, bb + j, 64);
        float w0 = __shfl(w0r, bb + j, 64);
        bf16x8 u0 = *(const bf16x8*)(Hs + (size_t)t0 * D + col);
#pragma unroll
        for (int p = 0; p < 8; ++p) a[p] = fmaf(bf2f((unsigned short)u0[p]), w0, a[p]);
    }
    if (cnt > 32) {               // Poisson(16) tail: rare
        for (int j2 = 0; j2 < cnt - 32; ++j2) {
            int   t0 = __shfl(s1r, bb + j2, 64);
            float w0 = __shfl(w1r, bb + j2, 64);
            bf16x8 u0 = *(const bf16x8*)(Hs + (size_t)t0 * D + col);
#pragma unroll
            for (int p = 0; p < 8; ++p) a[p] = fmaf(bf2f((unsigned short)u0[p]), w0, a[p]);
        }
    }

    if (mode == 0) {
        float4 b0 = *(const float4*)(bias + col);
        float4 b1 = *(const float4*)(bias + col + 4);
        float bf[8] = {b0.x, b0.y, b0.z, b0.w, b1.x, b1.y, b1.z, b1.w};
        bf16x8 o;
#pragma unroll
        for (int p = 0; p < 8; ++p) o[p] = (short)f2bf(fmaxf(a[p] + bf[p], 0.f));
        *(bf16x8*)(OutZ + (size_t)node * D + col) = o;
    } else {
        float4 o0, o1;
        o0.x = a[0]; o0.y = a[1]; o0.z = a[2]; o0.w = a[3];
        o1.x = a[4]; o1.y = a[5]; o1.z = a[6]; o1.w = a[7];
        float* Yp = OutY + (size_t)node * D + col;
        *(float4*)Yp = o0;
        *(float4*)(Yp + 4) = o1;
    }
}

extern "C" void kernel_launch(void* const* d_in, const int* in_sizes, int n_in,
                              void* d_out, int out_size, void* d_ws, size_t ws_size,
                              hipStream_t stream) {
    const float* x   = (const float*)d_in[0];
    const int*   ei  = (const int*)d_in[1];
    const float* W1  = (const float*)d_in[2];
    const float* b1  = (const float*)d_in[3];
    const float* Wmu = (const float*)d_in[4];
    const float* bmu = (const float*)d_in[5];
    const float* Wlv = (const float*)d_in[6];
    const float* blv = (const float*)d_in[7];
    const int* src = ei;
    const int* dst = ei + E_EDGES;

    const size_t NF = (size_t)N_NODES * D;  // 12.8M
    unsigned short* Hb = (unsigned short*)d_ws;   // [N,256] bf16
    unsigned short* Z  = Hb + NF;                 // [N,256] bf16
    float* Y = (float*)(Z + NF);                  // [N,256] fp32
    unsigned short* W1h = (unsigned short*)(Y + NF);
    unsigned short* W1l = W1h + 65536;
    unsigned short* Wch = W1l + 65536;
    unsigned short* Wcl = Wch + 65536;
    float* bcat = (float*)(Wcl + 65536);
    float* dinv = bcat + 256;
    int* cursor = (int*)(dinv + N_NODES);
    int* bucket = cursor + N_NODES;          // [N*CAP]
    float* mu = (float*)d_out;
    float* lv = mu + (size_t)N_NODES * L;

    // graph build: one atomic pass, degrees land in cursor
    zero_i<<<(N_NODES + 255) / 256, 256, 0, stream>>>(cursor, N_NODES);
    fill_fixed<<<(E_EDGES + 255) / 256, 256, 0, stream>>>(src, dst, cursor, bucket);
    dinv_fin<<<(N_NODES + 255) / 256, 256, 0, stream>>>(cursor, dinv);

    // weight prep
    prep_w<<<512, 256, 0, stream>>>(W1, Wmu, Wlv, bmu, blv, W1h, W1l, Wch, Wcl, bcat);

    const int gemm_blocks = (N_NODES + 63) / 64;     // 782
    const int gat_blocks  = N_NODES / 8;             // 6250 (50000 % 8 == 0)
    // layer 1: H = X@W1 (bf16 out)
    gemm_mfma<<<gemm_blocks, 256, 0, stream>>>(x, W1h, W1l, Hb,
                                               nullptr, nullptr, nullptr, N_NODES, 0);
    // Z = relu(P·H + b1)
    gather_pre<<<gat_blocks, 256, 0, stream>>>(Hb, bucket, cursor, dinv, b1,
                                               Z, nullptr, 0);
    // Y = P·Z (fp32)
    gather_pre<<<gat_blocks, 256, 0, stream>>>(Z, bucket, cursor, dinv, nullptr,
                                               nullptr, Y, 1);
    // heads: [mu|lv] = Y@[Wmu|Wlv] + [bmu|blv]
    gemm_mfma<<<gemm_blocks, 256, 0, stream>>>(Y, Wch, Wcl, nullptr,
                                               mu, lv, bcat, N_NODES, 1);
}